// Round 8
// baseline (3676.193 us; speedup 1.0000x reference)
//
#include <hip/hip_runtime.h>
#include <hip/hip_fp16.h>
#include <math.h>

// Problem constants
#define HD    1024      // hidden size
#define SEQL  512       // sequence length
#define NLAB  122       // labels
#define NWG   128       // workgroups in persistent recurrent kernel
#define TPW   512       // threads per WG (8 waves, 1 column per wave)

// Workspace layout (bytes). Total ≈ 18.9 MB.
#define OFF_MSG   ((size_t)0)          // h msg: 2 parities x 1024 u32 (tag<<16|fp16) = 8192 B
#define OFF_HALL  ((size_t)16384)      // h_all: 512*1024 fp32                  = 2097152 B
#define OFF_GATES ((size_t)2113536)    // gates_x: 512*4096 fp32 ([t][j][gate]) = 8388608 B
#define OFF_WR    ((size_t)10502144)   // W_r2h: fp16 weights, swizzled         = 8388608 B
// end = 18890752

typedef unsigned long long u64;
typedef int v4i __attribute__((ext_vector_type(4)));

// ---------------------------------------------------------------------------
// Prep: fp16 weights, laid out so lstm_rec wave v lane L reads its slice
// (4 gate rows x 16 k, column-block k = L*16..L*16+15) as 8 contiguous b128.
// uint4 index o2 = ((g*8+v)*8 + i2)*64 + L, i2 = row*2 + half:
//   8 fp16 = W_r[R][k..k+7], R = row*1024 + g*8 + v, k = L*16 + half*8
//   W_r[R][k] = W_ih[R][4096+k] + W_hh[R][k]
__global__ __launch_bounds__(256) void prep_wr(const float* __restrict__ W_ih,
                                               const float* __restrict__ W_hh,
                                               uint4* __restrict__ W_r2h) {
    int o2 = blockIdx.x * 256 + threadIdx.x;   // uint4 index, < 524288
    int g    = o2 >> 12;
    int rem  = o2 & 4095;
    int v    = rem >> 9;
    int i2   = (rem >> 6) & 7;
    int L    = rem & 63;
    int row  = i2 >> 1;
    int half_= i2 & 1;
    int R = (row << 10) + (g << 3) + v;
    int k = (L << 4) + (half_ << 3);
    const float* pa = W_ih + (size_t)R * 5120 + 4096 + k;
    const float* pb = W_hh + (size_t)R * 1024 + k;
    float4 a0 = *(const float4*)pa, a1 = *(const float4*)(pa + 4);
    float4 b0 = *(const float4*)pb, b1 = *(const float4*)(pb + 4);
    __half2 h0 = __floats2half2_rn(a0.x + b0.x, a0.y + b0.y);
    __half2 h1 = __floats2half2_rn(a0.z + b0.z, a0.w + b0.w);
    __half2 h2 = __floats2half2_rn(a1.x + b1.x, a1.y + b1.y);
    __half2 h3 = __floats2half2_rn(a1.z + b1.z, a1.w + b1.w);
    uint4 o;
    o.x = *(unsigned*)&h0; o.y = *(unsigned*)&h1;
    o.z = *(unsigned*)&h2; o.w = *(unsigned*)&h3;
    W_r2h[o2] = o;
}

// ---------------------------------------------------------------------------
// gates_x[t][j*4 + gate] = b[r] + sum_k feats[t][k] * W_ih[r][k]
//   (r = gate*1024 + j; [t][col][gate] layout -> lane 0 of the owning wave
//    loads its 4 gate values as one float4)
// feats = concat(x (2048), hi (2048)). 64x64 tile, BK=16, fp32 VALU.
__global__ __launch_bounds__(256) void gates_gemm(const float* __restrict__ x,
                                                  const float* __restrict__ hi,
                                                  const float* __restrict__ W_ih,
                                                  const float* __restrict__ b_ih,
                                                  const float* __restrict__ b_hh,
                                                  float* __restrict__ gates_x) {
    __shared__ float As[16][68];
    __shared__ float Bs[16][68];
    const int tid = threadIdx.x;
    const int r0 = blockIdx.x * 64;
    const int t0 = blockIdx.y * 64;
    const int tx = tid & 15, ty = tid >> 4;
    const int l   = tid & 63;
    const int kq4 = tid >> 6;

    float acc[4][4] = {};
    for (int kb = 0; kb < 4096; kb += 16) {
        int k = kb + kq4 * 4;
        const float* asrc = (k < 2048) ? (x  + (size_t)(t0 + l) * 2048 + k)
                                       : (hi + (size_t)(t0 + l) * 2048 + (k - 2048));
        float4 a4 = *(const float4*)asrc;
        float4 b4 = *(const float4*)(W_ih + (size_t)(r0 + l) * 5120 + k);
        __syncthreads();
        As[kq4 * 4 + 0][l] = a4.x; As[kq4 * 4 + 1][l] = a4.y;
        As[kq4 * 4 + 2][l] = a4.z; As[kq4 * 4 + 3][l] = a4.w;
        Bs[kq4 * 4 + 0][l] = b4.x; Bs[kq4 * 4 + 1][l] = b4.y;
        Bs[kq4 * 4 + 2][l] = b4.z; Bs[kq4 * 4 + 3][l] = b4.w;
        __syncthreads();
        #pragma unroll
        for (int kk = 0; kk < 16; ++kk) {
            float4 av = *(const float4*)&As[kk][ty * 4];
            float4 bv = *(const float4*)&Bs[kk][tx * 4];
            float a_[4] = {av.x, av.y, av.z, av.w};
            float b_[4] = {bv.x, bv.y, bv.z, bv.w};
            #pragma unroll
            for (int i = 0; i < 4; ++i)
                #pragma unroll
                for (int j = 0; j < 4; ++j)
                    acc[i][j] += a_[i] * b_[j];
        }
    }
    int r = r0 + tx * 4;
    float bias[4];
    #pragma unroll
    for (int j = 0; j < 4; ++j) bias[j] = b_ih[r + j] + b_hh[r + j];
    int gate = r >> 10;
    int jb   = r & 1023;          // 4 consecutive columns jb..jb+3, same gate
    #pragma unroll
    for (int i = 0; i < 4; ++i) {
        float* dst = gates_x + (size_t)(t0 + ty * 4 + i) * 4096;
        #pragma unroll
        for (int jj = 0; jj < 4; ++jj)
            dst[(jb + jj) * 4 + gate] = acc[i][jj] + bias[jj];
    }
}

// ---------------------------------------------------------------------------
// Persistent recurrent kernel — R7: wave-autonomous columns, ZERO barriers in
// the step loop. 128 WGs x 8 waves; wave v of WG g owns column j = g*8+v
// (4 gate rows x 1024 k). Lane L polls mailbox words [16L,16L+16) with 4
// dwordx4 sc0/sc1 loads (wave detects global step completion itself) and
// unpacks h_{s-1} DIRECTLY from the poll registers — no LDS h staging, no
// barrier, no 8-wave skew coupling. 4 row-accs reduced by 24-shuffle xor
// tree; lane 0 runs activations (c state in its VGPR) and publishes one u32
// (tag s+1 <<16 | fp16 h). fp16 weights in LDS (64 KB) halve the per-step
// DS stream (R6's 128 KB fp32 re-read ~1540 cyc was a hidden serial term);
// prefetched into regs before the poll (lgkm hides under vmcnt — proven).
// s_sleep(1) backoff on miss cuts MALL queue pressure.
// Mailbox word j of parity p: tag<<16 | fp16(h_j); 2 parities are safe: a
// producer can only publish tag s+1 after observing ALL tags s, which
// implies every wave consumed tags s-1 (the value being overwritten).
__global__ __launch_bounds__(512, 1) void lstm_rec(const float* __restrict__ gates_x,
                                                   const uint4* __restrict__ W_r2h,
                                                   float* __restrict__ h_all,
                                                   unsigned* h_msg) {
    const int g    = blockIdx.x;
    const int tid  = threadIdx.x;
    const int v    = tid >> 6;      // wave id 0..7
    const int lane = tid & 63;
    const int j    = (g << 3) + v;  // owned column
    __shared__ uint4 W_lds[4096];   // 64 KB fp16 weights

    // one-time stage: global (coalesced b128) -> LDS (flat copy)
    {
        const uint4* Wp = W_r2h + (size_t)g * 4096;
        #pragma unroll
        for (int i = 0; i < 8; ++i)
            W_lds[i * 512 + tid] = Wp[i * 512 + tid];
    }
    __syncthreads();   // staging is cross-wave; only barrier in the kernel

    const uint4* Wl = &W_lds[v * 512 + lane];
    float c = 0.f;                 // cell state (lane 0 of each wave)
    int budget = 1000000;          // anti-hang sweep budget

    for (int s = 0; s < SEQL; ++s) {
        asm volatile("" ::: "memory");
        // 1) weight ds_reads issue now, complete under the poll (lgkm vs vm)
        uint4 ww[8];
        #pragma unroll
        for (int i2 = 0; i2 < 8; ++i2)
            ww[i2] = Wl[i2 * 64];
        asm volatile("" ::: "memory");

        // 2) gx prefetch: lane 0 loads this column's 4 gate values (float4)
        float4 gxv = make_float4(0.f, 0.f, 0.f, 0.f);
        if (lane == 0)
            gxv = *(const float4*)(gates_x + (size_t)s * 4096 + j * 4);

        // 3) poll h_{s-1}: lane L owns words [16L,16L+16) of parity s&1
        v4i a0, a1, a2, a3;
        {
            const unsigned* base = h_msg + ((s & 1) << 10) + (lane << 4);
            u64 addr = (u64)base;
            const unsigned want = (unsigned)s;
            for (;;) {
                asm volatile(
                    "global_load_dwordx4 %0, %4, off sc0 sc1\n\t"
                    "global_load_dwordx4 %1, %4, off offset:16 sc0 sc1\n\t"
                    "global_load_dwordx4 %2, %4, off offset:32 sc0 sc1\n\t"
                    "global_load_dwordx4 %3, %4, off offset:48 sc0 sc1\n\t"
                    "s_waitcnt vmcnt(0)"
                    : "=&v"(a0), "=&v"(a1), "=&v"(a2), "=&v"(a3)
                    : "v"(addr)
                    : "memory");
                int ok = (((unsigned)a0.x >> 16) == want) & (((unsigned)a0.y >> 16) == want)
                       & (((unsigned)a0.z >> 16) == want) & (((unsigned)a0.w >> 16) == want)
                       & (((unsigned)a1.x >> 16) == want) & (((unsigned)a1.y >> 16) == want)
                       & (((unsigned)a1.z >> 16) == want) & (((unsigned)a1.w >> 16) == want)
                       & (((unsigned)a2.x >> 16) == want) & (((unsigned)a2.y >> 16) == want)
                       & (((unsigned)a2.z >> 16) == want) & (((unsigned)a2.w >> 16) == want)
                       & (((unsigned)a3.x >> 16) == want) & (((unsigned)a3.y >> 16) == want)
                       & (((unsigned)a3.z >> 16) == want) & (((unsigned)a3.w >> 16) == want);
                if (__all(ok)) break;
                if (--budget < 0) break;
                __builtin_amdgcn_s_sleep(1);
            }
        }

        // 4) unpack h from poll registers (fp16 low halves), matvec 4 rows
        float h16[16];
        {
            int aw[16] = {a0.x, a0.y, a0.z, a0.w, a1.x, a1.y, a1.z, a1.w,
                          a2.x, a2.y, a2.z, a2.w, a3.x, a3.y, a3.z, a3.w};
            #pragma unroll
            for (int kk = 0; kk < 16; ++kk)
                h16[kk] = __half2float(__ushort_as_half((unsigned short)(aw[kk] & 0xffff)));
        }
        float acc[4];
        #pragma unroll
        for (int r = 0; r < 4; ++r) {
            float sum = 0.f;
            #pragma unroll
            for (int hf = 0; hf < 2; ++hf) {
                uint4 q = ww[r * 2 + hf];
                unsigned uq[4] = {q.x, q.y, q.z, q.w};
                #pragma unroll
                for (int m = 0; m < 4; ++m) {
                    float2 wf = __half22float2(*(__half2*)&uq[m]);
                    int kb = hf * 8 + m * 2;
                    sum += wf.x * h16[kb] + wf.y * h16[kb + 1];
                }
            }
            acc[r] = sum;
        }

        // 5) reduce 4 accs across 64 lanes (xor tree)
        #pragma unroll
        for (int d = 1; d < 64; d <<= 1) {
            acc[0] += __shfl_xor(acc[0], d, 64);
            acc[1] += __shfl_xor(acc[1], d, 64);
            acc[2] += __shfl_xor(acc[2], d, 64);
            acc[3] += __shfl_xor(acc[3], d, 64);
        }

        // 6) lane 0: activations, publish
        if (lane == 0) {
            float gi = acc[0] + gxv.x, gf = acc[1] + gxv.y;
            float gc = acc[2] + gxv.z, go = acc[3] + gxv.w;
            float si = 1.f / (1.f + __expf(-gi));
            float sf = 1.f / (1.f + __expf(-gf));
            float so = 1.f / (1.f + __expf(-go));
            float tg = 2.f / (1.f + __expf(-2.f * gc)) - 1.f;   // tanh(gc)
            c = sf * c + si * tg;
            float th = 2.f / (1.f + __expf(-2.f * c)) - 1.f;    // tanh(c)
            float h = so * th;
            h_all[(size_t)s * HD + j] = h;
            unsigned hw = (unsigned)__half_as_ushort(__float2half_rn(h));
            unsigned m = ((unsigned)(s + 1) << 16) | hw;
            __hip_atomic_store(h_msg + (((s + 1) & 1) << 10) + j, m,
                               __ATOMIC_RELAXED, __HIP_MEMORY_SCOPE_AGENT);
        }
    }
}

// ---------------------------------------------------------------------------
// out[t][lab] = b_fc[lab] + sum_k h_all[t][k] * W_fc[lab][k]
__global__ __launch_bounds__(128) void fc_out(const float* __restrict__ h_all,
                                              const float* __restrict__ W_fc,
                                              const float* __restrict__ b_fc,
                                              float* __restrict__ out) {
    const int t = blockIdx.x;
    const int tid = threadIdx.x;
    __shared__ float4 h_s[256];
    const float4* hsrc = (const float4*)(h_all + (size_t)t * HD);
    h_s[tid] = hsrc[tid];
    h_s[tid + 128] = hsrc[tid + 128];
    __syncthreads();
    if (tid < NLAB) {
        float acc = b_fc[tid];
        const float4* wp = (const float4*)(W_fc + (size_t)tid * HD);
        #pragma unroll 8
        for (int k4 = 0; k4 < 256; ++k4) {
            float4 w = wp[k4];
            float4 h = h_s[k4];
            acc += w.x*h.x + w.y*h.y + w.z*h.z + w.w*h.w;
        }
        out[(size_t)t * NLAB + tid] = acc;
    }
}

// ---------------------------------------------------------------------------
extern "C" void kernel_launch(void* const* d_in, const int* in_sizes, int n_in,
                              void* d_out, int out_size, void* d_ws, size_t ws_size,
                              hipStream_t stream) {
    const float* x    = (const float*)d_in[0];
    const float* hi   = (const float*)d_in[1];
    const float* W_ih = (const float*)d_in[2];
    const float* W_hh = (const float*)d_in[3];
    const float* b_ih = (const float*)d_in[4];
    const float* b_hh = (const float*)d_in[5];
    const float* W_fc = (const float*)d_in[6];
    const float* b_fc = (const float*)d_in[7];
    float* out = (float*)d_out;

    char* ws = (char*)d_ws;
    unsigned* h_msg  = (unsigned*)(ws + OFF_MSG);
    float*    h_all  = (float*)(ws + OFF_HALL);
    float*    gates_x= (float*)(ws + OFF_GATES);
    uint4*    W_r2h  = (uint4*)(ws + OFF_WR);

    // zero the mailbox: h_{-1}=0 with tag 0 (ws re-poisoned 0xAA each call)
    hipMemsetAsync(d_ws, 0, 8192, stream);

    prep_wr<<<2048, 256, 0, stream>>>(W_ih, W_hh, W_r2h);

    dim3 gg(64, 8);
    gates_gemm<<<gg, 256, 0, stream>>>(x, hi, W_ih, b_ih, b_hh, gates_x);

    lstm_rec<<<NWG, TPW, 0, stream>>>(gates_x, W_r2h, h_all, h_msg);

    fc_out<<<SEQL, 128, 0, stream>>>(h_all, W_fc, b_fc, out);
}

// Round 9
// 1372.900 us; speedup vs baseline: 2.6777x; 2.6777x over previous
//
#include <hip/hip_runtime.h>
#include <hip/hip_fp16.h>
#include <math.h>

// Problem constants
#define HD    1024      // hidden size
#define SEQL  512       // sequence length
#define NLAB  122       // labels
#define NWG   128       // workgroups in persistent recurrent kernel
#define TPW   512       // threads per WG
#define JPW   8         // h-columns (j) per workgroup  (NWG*JPW == HD)

// Workspace layout (bytes).
#define OFF_MSG   ((size_t)0)          // h msg: 2*1024 u64 (tag<<32|h_bits)    = 16384 B
#define OFF_HALL  ((size_t)16384)      // h_all: 512*1024 fp32                  = 2097152 B
#define OFF_GATES ((size_t)2113536)    // gates_x: 512*4096 fp32 (swizzled)     = 8388608 B
#define OFF_WR    ((size_t)10502144)   // W_r2: 4096*1024 fp32 (swizzled)       = 16777216 B
#define OFF_W1H   ((size_t)27279360)   // W1h: 4096*4096 fp16                   = 33554432 B
#define OFF_FH    ((size_t)60833792)   // F_h: 512*4096 fp16                    = 4194304 B
#define WS_NEED   ((size_t)65028096)

typedef unsigned long long u64;
typedef _Float16 v8h __attribute__((ext_vector_type(8)));
typedef float v4f __attribute__((ext_vector_type(4)));

// ---------------------------------------------------------------------------
// Prep: W_r2 laid out [g][i][t] float4 (g<128, i<16, t<512) — R4 layout for
// lstm_rec LDS staging. (fp32: lstm weights stay full precision.)
__global__ __launch_bounds__(256) void prep_wr(const float* __restrict__ W_ih,
                                               const float* __restrict__ W_hh,
                                               float* __restrict__ W_r2) {
    int o = blockIdx.x * 256 + threadIdx.x;   // output float4 index, < 1048576
    int g   = o >> 13;            // 16*512 float4 per g
    int i   = (o >> 9) & 15;
    int t   = o & 511;
    int row = t & 31;
    int kq  = t >> 5;
    int gate = row >> 3;
    int jj   = row & 7;
    int R = (gate << 10) + (g << 3) + jj;
    int k = (kq << 6) + (i << 2);
    float4 wa = *(const float4*)(W_ih + (size_t)R * 5120 + 4096 + k);
    float4 wb = *(const float4*)(W_hh + (size_t)R * 1024 + k);
    float4 out;
    out.x = wa.x + wb.x; out.y = wa.y + wb.y; out.z = wa.z + wb.z; out.w = wa.w + wb.w;
    *(float4*)(W_r2 + (size_t)o * 4) = out;
}

// ---------------------------------------------------------------------------
// fp16 conversions for the MFMA gates GEMM.
static __device__ __forceinline__ uint4 pack8(float4 f0, float4 f1) {
    __half2 p0 = __floats2half2_rn(f0.x, f0.y);
    __half2 p1 = __floats2half2_rn(f0.z, f0.w);
    __half2 p2 = __floats2half2_rn(f1.x, f1.y);
    __half2 p3 = __floats2half2_rn(f1.z, f1.w);
    uint4 o;
    o.x = *(unsigned*)&p0; o.y = *(unsigned*)&p1;
    o.z = *(unsigned*)&p2; o.w = *(unsigned*)&p3;
    return o;
}

// F_h[t][k] = fp16(concat(x,hi)[t][k]); one uint4 (8 halfs) per thread.
__global__ __launch_bounds__(256) void prep_fh(const float* __restrict__ x,
                                               const float* __restrict__ hi,
                                               uint4* __restrict__ F_h) {
    int o = blockIdx.x * 256 + threadIdx.x;   // < 262144
    int t = o >> 9;
    int u = o & 511;
    const float* src = (u < 256) ? (x  + (size_t)t * 2048 + u * 8)
                                 : (hi + (size_t)t * 2048 + (u - 256) * 8);
    F_h[o] = pack8(*(const float4*)src, *(const float4*)(src + 4));
}

// W1h[r][k] = fp16(W_ih[r][k]), k<4096.
__global__ __launch_bounds__(256) void prep_w1h(const float* __restrict__ W_ih,
                                                uint4* __restrict__ W1h) {
    int o = blockIdx.x * 256 + threadIdx.x;   // < 2097152
    int r = o >> 9;
    int u = o & 511;
    const float* src = W_ih + (size_t)r * 5120 + u * 8;
    W1h[o] = pack8(*(const float4*)src, *(const float4*)(src + 4));
}

// ---------------------------------------------------------------------------
// MFMA gates GEMM: G[t][r] = bias[r] + sum_k F[t][k] * W1[r][k]
// (M=512, N=4096, K=4096; both operands K-major -> gemm_bt shape.)
// 128x128 tile, BK=32, fp16 in / fp32 acc; 4 waves in 2x2 quadrants, each
// wave 4x4 subtiles of 16x16x32. Store to the R4-swizzled gates_x layout:
//   sidx(r) = ((r&1023)>>3)*32 + (r>>10)*8 + (r&7)
__global__ __launch_bounds__(256) void gates_mfma(const uint4* __restrict__ F_u4,
                                                  const uint4* __restrict__ W_u4,
                                                  const float* __restrict__ b_ih,
                                                  const float* __restrict__ b_hh,
                                                  float* __restrict__ gates_x) {
    __shared__ uint4 AsB[1024];          // As = [0,512), Bs = [512,1024)
    const _Float16* Ash = (const _Float16*)AsB;          // 4096 halfs
    const _Float16* Bsh = Ash + 4096;
    const int tid  = threadIdx.x;
    const int wv   = tid >> 6;
    const int lane = tid & 63;
    const int wr   = wv & 1;             // m quadrant
    const int wc   = wv >> 1;            // n quadrant
    const int n0 = blockIdx.x * 128;
    const int t0 = blockIdx.y * 128;

    // staging map: uint4 slot u in [0,512): row = u>>2, kpart = u&3
    const int u0 = tid * 2, u1 = tid * 2 + 1;
    const uint4* aSrc0 = F_u4 + (size_t)(t0 + (u0 >> 2)) * 512 + (u0 & 3);
    const uint4* aSrc1 = F_u4 + (size_t)(t0 + (u1 >> 2)) * 512 + (u1 & 3);
    const uint4* bSrc0 = W_u4 + (size_t)(n0 + (u0 >> 2)) * 512 + (u0 & 3);
    const uint4* bSrc1 = W_u4 + (size_t)(n0 + (u1 >> 2)) * 512 + (u1 & 3);

    v4f acc[4][4];
    #pragma unroll
    for (int mi = 0; mi < 4; ++mi)
        #pragma unroll
        for (int ni = 0; ni < 4; ++ni)
            acc[mi][ni] = (v4f){0.f, 0.f, 0.f, 0.f};

    const int aoff = (wr * 64 + (lane & 15)) * 32 + (lane >> 4) * 8;
    const int boff = (wc * 64 + (lane & 15)) * 32 + (lane >> 4) * 8;

    for (int it = 0; it < 128; ++it) {    // kb = it*32, advance 4 uint4/row
        uint4 a0 = aSrc0[it * 4], a1 = aSrc1[it * 4];
        uint4 b0 = bSrc0[it * 4], b1 = bSrc1[it * 4];
        __syncthreads();                  // prior iter's frag reads done
        AsB[u0]       = a0; AsB[u1]       = a1;
        AsB[512 + u0] = b0; AsB[512 + u1] = b1;
        __syncthreads();
        v8h a8[4], b8[4];
        #pragma unroll
        for (int mi = 0; mi < 4; ++mi)
            a8[mi] = *(const v8h*)(Ash + aoff + mi * 16 * 32);
        #pragma unroll
        for (int ni = 0; ni < 4; ++ni)
            b8[ni] = *(const v8h*)(Bsh + boff + ni * 16 * 32);
        #pragma unroll
        for (int mi = 0; mi < 4; ++mi)
            #pragma unroll
            for (int ni = 0; ni < 4; ++ni)
                acc[mi][ni] = __builtin_amdgcn_mfma_f32_16x16x32_f16(
                                  a8[mi], b8[ni], acc[mi][ni], 0, 0, 0);
    }

    // epilogue: C row (t) = t0 + wr*64 + mi*16 + (lane>>4)*4 + reg
    //           C col (r) = n0 + wc*64 + ni*16 + (lane&15)
    #pragma unroll
    for (int ni = 0; ni < 4; ++ni) {
        int r = n0 + wc * 64 + ni * 16 + (lane & 15);
        int sidx = ((r & 1023) >> 3) * 32 + (r >> 10) * 8 + (r & 7);
        float bias = b_ih[r] + b_hh[r];
        #pragma unroll
        for (int mi = 0; mi < 4; ++mi) {
            int tb = t0 + wr * 64 + mi * 16 + ((lane >> 4) << 2);
            #pragma unroll
            for (int reg = 0; reg < 4; ++reg)
                gates_x[(size_t)(tb + reg) * 4096 + sidx] = acc[mi][ni][reg] + bias;
        }
    }
}

// ---------------------------------------------------------------------------
// Fallback fp32 VALU gates GEMM (used only if ws_size < WS_NEED).
__global__ __launch_bounds__(256) void gates_gemm_f32(const float* __restrict__ x,
                                                      const float* __restrict__ hi,
                                                      const float* __restrict__ W_ih,
                                                      const float* __restrict__ b_ih,
                                                      const float* __restrict__ b_hh,
                                                      float* __restrict__ gates_x) {
    __shared__ float As[16][68];
    __shared__ float Bs[16][68];
    const int tid = threadIdx.x;
    const int r0 = blockIdx.x * 64;
    const int t0 = blockIdx.y * 64;
    const int tx = tid & 15, ty = tid >> 4;
    const int l   = tid & 63;
    const int kq4 = tid >> 6;

    float acc[4][4] = {};
    for (int kb = 0; kb < 4096; kb += 16) {
        int k = kb + kq4 * 4;
        const float* asrc = (k < 2048) ? (x  + (size_t)(t0 + l) * 2048 + k)
                                       : (hi + (size_t)(t0 + l) * 2048 + (k - 2048));
        float4 a4 = *(const float4*)asrc;
        float4 b4 = *(const float4*)(W_ih + (size_t)(r0 + l) * 5120 + k);
        __syncthreads();
        As[kq4 * 4 + 0][l] = a4.x; As[kq4 * 4 + 1][l] = a4.y;
        As[kq4 * 4 + 2][l] = a4.z; As[kq4 * 4 + 3][l] = a4.w;
        Bs[kq4 * 4 + 0][l] = b4.x; Bs[kq4 * 4 + 1][l] = b4.y;
        Bs[kq4 * 4 + 2][l] = b4.z; Bs[kq4 * 4 + 3][l] = b4.w;
        __syncthreads();
        #pragma unroll
        for (int kk = 0; kk < 16; ++kk) {
            float4 av = *(const float4*)&As[kk][ty * 4];
            float4 bv = *(const float4*)&Bs[kk][tx * 4];
            float a_[4] = {av.x, av.y, av.z, av.w};
            float b_[4] = {bv.x, bv.y, bv.z, bv.w};
            #pragma unroll
            for (int i = 0; i < 4; ++i)
                #pragma unroll
                for (int j = 0; j < 4; ++j)
                    acc[i][j] += a_[i] * b_[j];
        }
    }
    int r = r0 + tx * 4;
    float bias[4];
    #pragma unroll
    for (int j = 0; j < 4; ++j) bias[j] = b_ih[r + j] + b_hh[r + j];
    int gate = r >> 10;
    int g    = (r & 1023) >> 3;
    int jj   = r & 7;
    int sidx = g * 32 + gate * 8 + jj;
    #pragma unroll
    for (int i = 0; i < 4; ++i) {
        float4 o;
        o.x = acc[i][0] + bias[0]; o.y = acc[i][1] + bias[1];
        o.z = acc[i][2] + bias[2]; o.w = acc[i][3] + bias[3];
        *(float4*)(gates_x + (size_t)(t0 + ty * 4 + i) * 4096 + sidx) = o;
    }
}

// ---------------------------------------------------------------------------
// Persistent recurrent kernel — R4 verbatim (best measured: 1089 us).
// 128 WGs x 512 threads; weights in LDS prefetched to regs before the poll;
// tag-in-word fp32 mailbox, 2 contiguous u64/thread, staggered double-sample.
__global__ __launch_bounds__(512, 1) void lstm_rec(const float* __restrict__ gates_x,
                                                   const float* __restrict__ W_r2,
                                                   float* __restrict__ h_all,
                                                   u64* h_msg) {
    const int g   = blockIdx.x;
    const int tid = threadIdx.x;
    const int row = tid & 31;    // gate = row>>3, jj = row&7
    const int kq  = tid >> 5;    // k-slice [kq*64, kq*64+64)
    __shared__ float4 W_lds[16][TPW];   // 128 KB, lane-contiguous
    __shared__ float4 h_s4[256];        // h_{s-1}; h_s4[q] = h[4q..4q+3]
    __shared__ float  partial[8][36];   // [wave][row]
    float* h_sf = (float*)h_s4;

    {
        const float4* Wp = (const float4*)W_r2 + (size_t)g * 8192;
        #pragma unroll
        for (int i = 0; i < 16; ++i)
            W_lds[i][tid] = Wp[i * TPW + tid];
    }
    __syncthreads();

    float c = 0.f;
    int budget = 4000000;

    for (int s = 0; s < SEQL; ++s) {
        asm volatile("" ::: "memory");
        float4 w[16];
        #pragma unroll
        for (int i = 0; i < 16; ++i)
            w[i] = W_lds[i][tid];
        asm volatile("" ::: "memory");

        float gx = 0.f;
        if (tid < 32)
            gx = gates_x[(size_t)s * 4096 + g * 32 + tid];

        {
            const u64* buf = h_msg + (size_t)(s & 1) * HD + tid * 2;
            const unsigned want = (unsigned)s;
            u64 r0, r1;
            for (;;) {
                u64 a0 = __hip_atomic_load(buf + 0, __ATOMIC_RELAXED, __HIP_MEMORY_SCOPE_AGENT);
                u64 a1 = __hip_atomic_load(buf + 1, __ATOMIC_RELAXED, __HIP_MEMORY_SCOPE_AGENT);
                u64 b0 = __hip_atomic_load(buf + 0, __ATOMIC_RELAXED, __HIP_MEMORY_SCOPE_AGENT);
                u64 b1 = __hip_atomic_load(buf + 1, __ATOMIC_RELAXED, __HIP_MEMORY_SCOPE_AGENT);
                if ((unsigned)(a0 >> 32) == want && (unsigned)(a1 >> 32) == want) {
                    r0 = a0; r1 = a1; break;
                }
                if ((unsigned)(b0 >> 32) == want && (unsigned)(b1 >> 32) == want) {
                    r0 = b0; r1 = b1; break;
                }
                if (--budget < 0) { r0 = b0; r1 = b1; break; }
            }
            h_sf[2 * tid + 0] = __uint_as_float((unsigned)r0);
            h_sf[2 * tid + 1] = __uint_as_float((unsigned)r1);
        }
        __syncthreads();

        float a0 = 0.f, a1 = 0.f, a2 = 0.f, a3 = 0.f;
        #pragma unroll
        for (int i = 0; i < 16; ++i) {
            float4 h4 = h_s4[kq * 16 + i];
            a0 += w[i].x * h4.x;
            a1 += w[i].y * h4.y;
            a2 += w[i].z * h4.z;
            a3 += w[i].w * h4.w;
        }
        float p = (a0 + a1) + (a2 + a3);
        p += __shfl_xor(p, 32, 64);
        if ((tid & 32) == 0)
            partial[tid >> 6][row] = p;
        __syncthreads();

        if (tid < 32) {
            float sum = gx;
            #pragma unroll
            for (int q = 0; q < 8; ++q) sum += partial[q][tid];
            int jj = tid & 7;
            float vf = __shfl(sum,  8 + jj, 64);
            float vg = __shfl(sum, 16 + jj, 64);
            float vo = __shfl(sum, 24 + jj, 64);
            if (tid < 8) {
                float si = 1.f / (1.f + __expf(-sum));
                float sf = 1.f / (1.f + __expf(-vf));
                float so = 1.f / (1.f + __expf(-vo));
                float tg = 2.f / (1.f + __expf(-2.f * vg)) - 1.f;
                c = sf * c + si * tg;
                float th = 2.f / (1.f + __expf(-2.f * c)) - 1.f;
                float h = so * th;
                int j = g * JPW + tid;
                h_all[(size_t)s * HD + j] = h;
                u64 m = ((u64)(unsigned)(s + 1) << 32)
                      | (u64)__float_as_uint(h);
                __hip_atomic_store(h_msg + (size_t)((s + 1) & 1) * HD + j, m,
                                   __ATOMIC_RELAXED, __HIP_MEMORY_SCOPE_AGENT);
            }
        }
    }
}

// ---------------------------------------------------------------------------
// out[t][lab] = b_fc[lab] + sum_k h_all[t][k] * W_fc[lab][k]
__global__ __launch_bounds__(128) void fc_out(const float* __restrict__ h_all,
                                              const float* __restrict__ W_fc,
                                              const float* __restrict__ b_fc,
                                              float* __restrict__ out) {
    const int t = blockIdx.x;
    const int tid = threadIdx.x;
    __shared__ float4 h_s[256];
    const float4* hsrc = (const float4*)(h_all + (size_t)t * HD);
    h_s[tid] = hsrc[tid];
    h_s[tid + 128] = hsrc[tid + 128];
    __syncthreads();
    if (tid < NLAB) {
        float acc = b_fc[tid];
        const float4* wp = (const float4*)(W_fc + (size_t)tid * HD);
        #pragma unroll 8
        for (int k4 = 0; k4 < 256; ++k4) {
            float4 w = wp[k4];
            float4 h = h_s[k4];
            acc += w.x*h.x + w.y*h.y + w.z*h.z + w.w*h.w;
        }
        out[(size_t)t * NLAB + tid] = acc;
    }
}

// ---------------------------------------------------------------------------
extern "C" void kernel_launch(void* const* d_in, const int* in_sizes, int n_in,
                              void* d_out, int out_size, void* d_ws, size_t ws_size,
                              hipStream_t stream) {
    const float* x    = (const float*)d_in[0];
    const float* hi   = (const float*)d_in[1];
    const float* W_ih = (const float*)d_in[2];
    const float* W_hh = (const float*)d_in[3];
    const float* b_ih = (const float*)d_in[4];
    const float* b_hh = (const float*)d_in[5];
    const float* W_fc = (const float*)d_in[6];
    const float* b_fc = (const float*)d_in[7];
    float* out = (float*)d_out;

    char* ws = (char*)d_ws;
    u64*   h_msg   = (u64*)(ws + OFF_MSG);
    float* h_all   = (float*)(ws + OFF_HALL);
    float* gates_x = (float*)(ws + OFF_GATES);
    float* W_r2    = (float*)(ws + OFF_WR);
    uint4* W1h     = (uint4*)(ws + OFF_W1H);
    uint4* F_h     = (uint4*)(ws + OFF_FH);

    // zero the mailbox: h_{-1}=0 with tag 0 (ws re-poisoned 0xAA each call)
    hipMemsetAsync(d_ws, 0, 16384, stream);

    prep_wr<<<4096, 256, 0, stream>>>(W_ih, W_hh, W_r2);

    if (ws_size >= WS_NEED) {
        prep_fh<<<1024, 256, 0, stream>>>(x, hi, F_h);
        prep_w1h<<<8192, 256, 0, stream>>>(W_ih, W1h);
        dim3 gg(32, 4);   // n-tiles x t-tiles
        gates_mfma<<<gg, 256, 0, stream>>>(F_h, W1h, b_ih, b_hh, gates_x);
    } else {
        dim3 gg(64, 8);
        gates_gemm_f32<<<gg, 256, 0, stream>>>(x, hi, W_ih, b_ih, b_hh, gates_x);
    }

    lstm_rec<<<NWG, TPW, 0, stream>>>(gates_x, W_r2, h_all, h_msg);

    fc_out<<<SEQL, 128, 0, stream>>>(h_all, W_fc, b_fc, out);
}